// Round 2
// baseline (3923.944 us; speedup 1.0000x reference)
//
#include <hip/hip_runtime.h>
#include <hip/hip_bf16.h>

#define NN 3072
#define EE 49152
#define DD 256
#define OO 512
#define HH 8
#define DHH 32
#define NETT 5
#define TQ 4

// ---------------- embedding: h[n,d] = x[n]*emb_w[d] + emb_b[d] ----------------
__global__ void k_embed(const float* __restrict__ x, const float* __restrict__ w,
                        const float* __restrict__ b, float* __restrict__ h){
    int i = blockIdx.x * 256 + threadIdx.x;   // i < NN*DD
    int n = i >> 8, d = i & 255;
    h[i] = x[n] * w[d] + b[d];
}

// ---------------- hp = h + pos ----------------
__global__ void k_addpos(const float* __restrict__ h, const float* __restrict__ pos,
                         float* __restrict__ hp){
    int i = blockIdx.x * 256 + threadIdx.x;
    hp[i] = h[i] + pos[i];
}

// ---------------- CSR build ----------------
__global__ void k_count(const int* __restrict__ ei, int* __restrict__ cnt){
    int e = blockIdx.x * 256 + threadIdx.x;
    if (e < EE) atomicAdd(&cnt[ei[e]], 1);
}

__global__ void k_scan(const int* __restrict__ cnt, int* __restrict__ rp){
    __shared__ int part[256];
    int tid = threadIdx.x;
    int base = tid * 12;
    int loc[12]; int s = 0;
    for (int i = 0; i < 12; i++){ loc[i] = s; s += cnt[base + i]; }
    part[tid] = s; __syncthreads();
    if (tid == 0){ int a = 0; for (int i = 0; i < 256; i++){ int t = part[i]; part[i] = a; a += t; } }
    __syncthreads();
    int b = part[tid];
    for (int i = 0; i < 12; i++) rp[base + i] = b + loc[i];
    if (tid == 255) rp[NN] = b + s;
}

__global__ void k_fill(const int* __restrict__ ei, const int* __restrict__ et,
                       const int* __restrict__ rp, int* __restrict__ cur,
                       int* __restrict__ e_dst, int* __restrict__ e_typ){
    int e = blockIdx.x * 256 + threadIdx.x;
    if (e < EE){
        int s = ei[e], d = ei[EE + e];
        int p = atomicAdd(&cur[s], 1);
        int idx = rp[s] + p;
        e_dst[idx] = d; e_typ[idx] = et[e];
    }
}

// ---------------- GEMM: C[4 rows] = A @ W + bias ----------------
// A fp32 [NN, DD], W fp32 [DD, M], bias fp32 [M]. 4 rows per block, 256 threads.
template<int M>
__global__ __launch_bounds__(256) void k_gemm(const float* __restrict__ A,
                                              const float* __restrict__ W,
                                              const float* __restrict__ bias,
                                              float* __restrict__ C){
    int n0 = blockIdx.x * 4;
    __shared__ float a[4][DD];
    int tid = threadIdx.x;
    for (int i = tid; i < 4 * DD; i += 256) a[i >> 8][i & 255] = A[(n0 + (i >> 8)) * DD + (i & 255)];
    __syncthreads();
    for (int j = tid; j < M; j += 256){
        float bz = bias[j];
        float a0 = bz, a1 = bz, a2 = bz, a3 = bz;
        #pragma unroll 8
        for (int k = 0; k < DD; k++){
            float wv = W[k * M + j];
            a0 += a[0][k] * wv; a1 += a[1][k] * wv; a2 += a[2][k] * wv; a3 += a[3][k] * wv;
        }
        C[(n0 + 0) * M + j] = a0;
        C[(n0 + 1) * M + j] = a1;
        C[(n0 + 2) * M + j] = a2;
        C[(n0 + 3) * M + j] = a3;
    }
}

// ---------------- residual + layernorm: h = LN(h + t) * g + b ----------------
__global__ __launch_bounds__(256) void k_ln_res(float* __restrict__ h, const float* __restrict__ t,
                                                const float* __restrict__ g, const float* __restrict__ b){
    int n = blockIdx.x, d = threadIdx.x;
    __shared__ float red[256];
    float v = h[n * 256 + d] + t[n * 256 + d];
    red[d] = v; __syncthreads();
    for (int s = 128; s > 0; s >>= 1){ if (d < s) red[d] += red[d + s]; __syncthreads(); }
    float mean = red[0] * (1.0f / 256.0f); __syncthreads();
    float c = v - mean;
    red[d] = c * c; __syncthreads();
    for (int s = 128; s > 0; s >>= 1){ if (d < s) red[d] += red[d + s]; __syncthreads(); }
    float var = red[0] * (1.0f / 256.0f);
    h[n * 256 + d] = c * rsqrtf(var + 1e-5f) * g[d] + b[d];
}

// ---------------- local (per-head, community-masked, edge-biased) attention ----------------
// grid (NN/TQ, HH), 256 threads. Full score rows in LDS, exact 2-pass softmax.
__global__ __launch_bounds__(256) void k_local_attn(
        const float* __restrict__ q, const float* __restrict__ k, const float* __restrict__ v,
        const int* __restrict__ comm, const int* __restrict__ rp,
        const int* __restrict__ e_dst, const int* __restrict__ e_typ,
        const float* __restrict__ eb, float* __restrict__ o){
    int hh = blockIdx.y;
    int n0 = blockIdx.x * TQ;
    int tid = threadIdx.x;
    __shared__ float sc[TQ][NN];
    __shared__ float qs[TQ][DHH];
    __shared__ float rbuf[256];
    __shared__ int qc[TQ];
    __shared__ float sm[TQ];

    if (tid < TQ * DHH){
        int qi = tid >> 5, d = tid & 31;
        qs[qi][d] = q[(n0 + qi) * DD + hh * DHH + d];
    }
    if (tid < TQ) qc[tid] = comm[n0 + tid];
    __syncthreads();

    const float scale = 0.17677669529663687f; // 1/sqrt(32)
    for (int m = tid; m < NN; m += 256){
        int cm = comm[m];
        bool c0 = (cm == qc[0]), c1 = (cm == qc[1]), c2 = (cm == qc[2]), c3 = (cm == qc[3]);
        float s0 = -INFINITY, s1 = -INFINITY, s2 = -INFINITY, s3 = -INFINITY;
        if (c0 | c1 | c2 | c3){
            const float4* kr = (const float4*)(k + (size_t)m * DD + hh * DHH);
            float t0 = 0, t1 = 0, t2 = 0, t3 = 0;
            #pragma unroll
            for (int d4 = 0; d4 < DHH / 4; d4++){
                float4 kv = kr[d4];
                float4 q0 = ((const float4*)qs[0])[d4];
                float4 q1 = ((const float4*)qs[1])[d4];
                float4 q2 = ((const float4*)qs[2])[d4];
                float4 q3 = ((const float4*)qs[3])[d4];
                t0 += q0.x * kv.x + q0.y * kv.y + q0.z * kv.z + q0.w * kv.w;
                t1 += q1.x * kv.x + q1.y * kv.y + q1.z * kv.z + q1.w * kv.w;
                t2 += q2.x * kv.x + q2.y * kv.y + q2.z * kv.z + q2.w * kv.w;
                t3 += q3.x * kv.x + q3.y * kv.y + q3.z * kv.z + q3.w * kv.w;
            }
            if (c0) s0 = t0 * scale;
            if (c1) s1 = t1 * scale;
            if (c2) s2 = t2 * scale;
            if (c3) s3 = t3 * scale;
        }
        sc[0][m] = s0; sc[1][m] = s1; sc[2][m] = s2; sc[3][m] = s3;
    }
    __syncthreads();

    // edge-type bias (duplicates accumulate; masked entries stay -inf)
    for (int qi = 0; qi < TQ; qi++){
        int n = n0 + qi;
        for (int e = rp[n] + tid; e < rp[n + 1]; e += 256){
            atomicAdd(&sc[qi][e_dst[e]], eb[e_typ[e] * HH + hh]);
        }
    }
    __syncthreads();

    // exact softmax per row
    for (int qi = 0; qi < TQ; qi++){
        float lm = -INFINITY;
        for (int m = tid; m < NN; m += 256) lm = fmaxf(lm, sc[qi][m]);
        rbuf[tid] = lm; __syncthreads();
        for (int s = 128; s > 0; s >>= 1){ if (tid < s) rbuf[tid] = fmaxf(rbuf[tid], rbuf[tid + s]); __syncthreads(); }
        float mx = rbuf[0]; __syncthreads();
        float ls = 0;
        for (int m = tid; m < NN; m += 256){
            float e_ = __expf(sc[qi][m] - mx);
            sc[qi][m] = e_;
            ls += e_;
        }
        rbuf[tid] = ls; __syncthreads();
        for (int s = 128; s > 0; s >>= 1){ if (tid < s) rbuf[tid] += rbuf[tid + s]; __syncthreads(); }
        if (tid == 0) sm[qi] = rbuf[0];
        __syncthreads();
    }

    // PV: 8 m-groups x 32 dims
    int grp = tid >> 5, d = tid & 31;
    float acc0 = 0, acc1 = 0, acc2 = 0, acc3 = 0;
    for (int m = grp; m < NN; m += 8){
        float w0 = sc[0][m], w1 = sc[1][m], w2 = sc[2][m], w3 = sc[3][m];
        if (w0 != 0.f || w1 != 0.f || w2 != 0.f || w3 != 0.f){
            float vv = v[(size_t)m * DD + hh * DHH + d];
            acc0 += w0 * vv; acc1 += w1 * vv; acc2 += w2 * vv; acc3 += w3 * vv;
        }
    }
    float accs[4] = {acc0, acc1, acc2, acc3};
    for (int qi = 0; qi < TQ; qi++){
        rbuf[grp * 32 + d] = accs[qi]; __syncthreads();
        if (grp == 0){
            float s = 0;
            #pragma unroll
            for (int g2 = 0; g2 < 8; g2++) s += rbuf[g2 * 32 + d];
            o[(n0 + qi) * DD + hh * DHH + d] = s / sm[qi];
        }
        __syncthreads();
    }
}

// ---------------- global (cross-community) attention ----------------
// grid NN/TQ, 256 threads. Full 256-dim dots, scale 1/sqrt(32) per reference.
__global__ __launch_bounds__(256) void k_glob_attn(
        const float* __restrict__ Q, const float* __restrict__ K, const float* __restrict__ V,
        const int* __restrict__ comm, float* __restrict__ o){
    int n0 = blockIdx.x * TQ;
    int tid = threadIdx.x;
    __shared__ float sc[TQ][NN];
    __shared__ float qs[TQ][DD];
    __shared__ float rbuf[256];
    __shared__ int qc[TQ];
    __shared__ float sm[TQ];

    for (int i = tid; i < TQ * DD; i += 256) qs[i >> 8][i & 255] = Q[(n0 + (i >> 8)) * DD + (i & 255)];
    if (tid < TQ) qc[tid] = comm[n0 + tid];
    __syncthreads();

    const float scale = 0.17677669529663687f; // 1/sqrt(32) per reference
    for (int m = tid; m < NN; m += 256){
        int cm = comm[m];
        const float4* kr = (const float4*)(K + (size_t)m * DD);
        float t0 = 0, t1 = 0, t2 = 0, t3 = 0;
        #pragma unroll 8
        for (int d4 = 0; d4 < DD / 4; d4++){
            float4 kv = kr[d4];
            float4 q0 = ((const float4*)qs[0])[d4];
            float4 q1 = ((const float4*)qs[1])[d4];
            float4 q2 = ((const float4*)qs[2])[d4];
            float4 q3 = ((const float4*)qs[3])[d4];
            t0 += q0.x * kv.x + q0.y * kv.y + q0.z * kv.z + q0.w * kv.w;
            t1 += q1.x * kv.x + q1.y * kv.y + q1.z * kv.z + q1.w * kv.w;
            t2 += q2.x * kv.x + q2.y * kv.y + q2.z * kv.z + q2.w * kv.w;
            t3 += q3.x * kv.x + q3.y * kv.y + q3.z * kv.z + q3.w * kv.w;
        }
        sc[0][m] = (cm != qc[0]) ? t0 * scale : -INFINITY;
        sc[1][m] = (cm != qc[1]) ? t1 * scale : -INFINITY;
        sc[2][m] = (cm != qc[2]) ? t2 * scale : -INFINITY;
        sc[3][m] = (cm != qc[3]) ? t3 * scale : -INFINITY;
    }
    __syncthreads();

    for (int qi = 0; qi < TQ; qi++){
        float lm = -INFINITY;
        for (int m = tid; m < NN; m += 256) lm = fmaxf(lm, sc[qi][m]);
        rbuf[tid] = lm; __syncthreads();
        for (int s = 128; s > 0; s >>= 1){ if (tid < s) rbuf[tid] = fmaxf(rbuf[tid], rbuf[tid + s]); __syncthreads(); }
        float mx = rbuf[0]; __syncthreads();
        float ls = 0;
        for (int m = tid; m < NN; m += 256){
            float e_ = __expf(sc[qi][m] - mx);
            sc[qi][m] = e_;
            ls += e_;
        }
        rbuf[tid] = ls; __syncthreads();
        for (int s = 128; s > 0; s >>= 1){ if (tid < s) rbuf[tid] += rbuf[tid + s]; __syncthreads(); }
        if (tid == 0) sm[qi] = rbuf[0];
        __syncthreads();
    }

    // PV: thread = output dim (DD == 256 == blockDim)
    float a0 = 0, a1 = 0, a2 = 0, a3 = 0;
    #pragma unroll 4
    for (int m = 0; m < NN; m++){
        float vv = V[(size_t)m * DD + tid];
        a0 += sc[0][m] * vv;
        a1 += sc[1][m] * vv;
        a2 += sc[2][m] * vv;
        a3 += sc[3][m] * vv;
    }
    o[(n0 + 0) * DD + tid] = a0 / sm[0];
    o[(n0 + 1) * DD + tid] = a1 / sm[1];
    o[(n0 + 2) * DD + tid] = a2 / sm[2];
    o[(n0 + 3) * DD + tid] = a3 / sm[3];
}

// ---------------- host ----------------
extern "C" void kernel_launch(void* const* d_in, const int* in_sizes, int n_in,
                              void* d_out, int out_size, void* d_ws, size_t ws_size,
                              hipStream_t stream){
    const float* x        = (const float*)d_in[0];
    const int*   ei       = (const int*)  d_in[1];
    const int*   et       = (const int*)  d_in[2];
    const float* pos      = (const float*)d_in[3];
    const int*   comm     = (const int*)  d_in[4];
    // d_in[5] adj_matrix unused (zeros)
    const float* emb_w    = (const float*)d_in[6];
    const float* emb_b    = (const float*)d_in[7];
    const float* loc_qw   = (const float*)d_in[8];
    const float* loc_qb   = (const float*)d_in[9];
    const float* loc_kw   = (const float*)d_in[10];
    const float* loc_kb   = (const float*)d_in[11];
    const float* loc_vw   = (const float*)d_in[12];
    const float* loc_vb   = (const float*)d_in[13];
    const float* loc_ow   = (const float*)d_in[14];
    const float* loc_ob   = (const float*)d_in[15];
    const float* loc_eb   = (const float*)d_in[16];
    const float* loc_ln_g = (const float*)d_in[17];
    const float* loc_ln_b = (const float*)d_in[18];
    const float* glob_qw  = (const float*)d_in[19];
    const float* glob_qb  = (const float*)d_in[20];
    const float* glob_kw  = (const float*)d_in[21];
    const float* glob_kb  = (const float*)d_in[22];
    const float* glob_vw  = (const float*)d_in[23];
    const float* glob_vb  = (const float*)d_in[24];
    const float* glob_ow  = (const float*)d_in[25];
    const float* glob_ob  = (const float*)d_in[26];
    const float* glob_ln_g= (const float*)d_in[27];
    const float* glob_ln_b= (const float*)d_in[28];
    const float* out_w    = (const float*)d_in[29];
    const float* out_b    = (const float*)d_in[30];

    // workspace carve (fp32 intermediates)
    float* h   = (float*)d_ws;            // NN*DD
    float* hp  = h   + NN * DD;
    float* qb_ = hp  + NN * DD;
    float* kb_ = qb_ + NN * DD;
    float* vb_ = kb_ + NN * DD;
    float* ob_ = vb_ + NN * DD;
    float* tb_ = ob_ + NN * DD;
    int* cnt   = (int*)(tb_ + NN * DD);   // NN
    int* cur   = cnt + NN;                // NN
    int* rp    = cur + NN;                // NN+1
    int* e_dst = rp + (NN + 1);           // EE
    int* e_typ = e_dst + EE;              // EE

    hipMemsetAsync(cnt, 0, sizeof(int) * 2 * NN, stream);

    k_embed<<<NN * DD / 256, 256, 0, stream>>>(x, emb_w, emb_b, h);
    k_count<<<EE / 256, 256, 0, stream>>>(ei, cnt);
    k_scan<<<1, 256, 0, stream>>>(cnt, rp);
    k_fill<<<EE / 256, 256, 0, stream>>>(ei, et, rp, cur, e_dst, e_typ);

    for (int l = 0; l < 2; l++){
        k_addpos<<<NN * DD / 256, 256, 0, stream>>>(h, pos, hp);
        k_gemm<DD><<<NN / 4, 256, 0, stream>>>(hp, loc_qw + l * DD * DD, loc_qb + l * DD, qb_);
        k_gemm<DD><<<NN / 4, 256, 0, stream>>>(hp, loc_kw + l * DD * DD, loc_kb + l * DD, kb_);
        k_gemm<DD><<<NN / 4, 256, 0, stream>>>(hp, loc_vw + l * DD * DD, loc_vb + l * DD, vb_);
        k_local_attn<<<dim3(NN / TQ, HH), 256, 0, stream>>>(qb_, kb_, vb_, comm, rp, e_dst, e_typ,
                                                            loc_eb + l * NETT * HH, ob_);
        k_gemm<DD><<<NN / 4, 256, 0, stream>>>(ob_, loc_ow + l * DD * DD, loc_ob + l * DD, tb_);
        k_ln_res<<<NN, 256, 0, stream>>>(h, tb_, loc_ln_g + l * DD, loc_ln_b + l * DD);
    }

    for (int g = 0; g < 2; g++){
        k_gemm<DD><<<NN / 4, 256, 0, stream>>>(h, glob_qw + g * DD * DD, glob_qb + g * DD, qb_);
        k_gemm<DD><<<NN / 4, 256, 0, stream>>>(h, glob_kw + g * DD * DD, glob_kb + g * DD, kb_);
        k_gemm<DD><<<NN / 4, 256, 0, stream>>>(h, glob_vw + g * DD * DD, glob_vb + g * DD, vb_);
        k_glob_attn<<<NN / TQ, 256, 0, stream>>>(qb_, kb_, vb_, comm, ob_);
        k_gemm<DD><<<NN / 4, 256, 0, stream>>>(ob_, glob_ow + g * DD * DD, glob_ob + g * DD, tb_);
        k_ln_res<<<NN, 256, 0, stream>>>(h, tb_, glob_ln_g + g * DD, glob_ln_b + g * DD);
    }

    k_gemm<OO><<<NN / 4, 256, 0, stream>>>(h, out_w, out_b, (float*)d_out);
}

// Round 3
// 3135.385 us; speedup vs baseline: 1.2515x; 1.2515x over previous
//
#include <hip/hip_runtime.h>
#include <hip/hip_bf16.h>

#define NN 3072
#define EE 49152
#define DD 256
#define OO 512
#define HH 8
#define DHH 32
#define NETT 5
#define NC 8
#define TQ 4
#define TQ2 8      // queries per local-attn block
#define NCMAX 768  // community size cap (binomial mean 384, sd 18 -> 768 is 21 sigma)

// ---------------- embedding: h[n,d] = x[n]*emb_w[d] + emb_b[d] ----------------
__global__ void k_embed(const float* __restrict__ x, const float* __restrict__ w,
                        const float* __restrict__ b, float* __restrict__ h){
    int i = blockIdx.x * 256 + threadIdx.x;   // i < NN*DD
    int n = i >> 8, d = i & 255;
    h[i] = x[n] * w[d] + b[d];
}

// ---------------- hp = h + pos ----------------
__global__ void k_addpos(const float* __restrict__ h, const float* __restrict__ pos,
                         float* __restrict__ hp){
    int i = blockIdx.x * 256 + threadIdx.x;
    hp[i] = h[i] + pos[i];
}

// ---------------- CSR build (per-node edge lists) ----------------
__global__ void k_count(const int* __restrict__ ei, int* __restrict__ cnt){
    int e = blockIdx.x * 256 + threadIdx.x;
    if (e < EE) atomicAdd(&cnt[ei[e]], 1);
}

__global__ void k_scan(const int* __restrict__ cnt, int* __restrict__ rp){
    __shared__ int part[256];
    int tid = threadIdx.x;
    int base = tid * 12;
    int loc[12]; int s = 0;
    for (int i = 0; i < 12; i++){ loc[i] = s; s += cnt[base + i]; }
    part[tid] = s; __syncthreads();
    if (tid == 0){ int a = 0; for (int i = 0; i < 256; i++){ int t = part[i]; part[i] = a; a += t; } }
    __syncthreads();
    int b = part[tid];
    for (int i = 0; i < 12; i++) rp[base + i] = b + loc[i];
    if (tid == 255) rp[NN] = b + s;
}

__global__ void k_fill(const int* __restrict__ ei, const int* __restrict__ et,
                       const int* __restrict__ rp, int* __restrict__ cur,
                       int* __restrict__ e_dst, int* __restrict__ e_typ){
    int e = blockIdx.x * 256 + threadIdx.x;
    if (e < EE){
        int s = ei[e], d = ei[EE + e];
        int p = atomicAdd(&cur[s], 1);
        int idx = rp[s] + p;
        e_dst[idx] = d; e_typ[idx] = et[e];
    }
}

// ---------------- community sort: perm / inv / cstart ----------------
__global__ void k_ccount(const int* __restrict__ comm, int* __restrict__ ccnt){
    int n = blockIdx.x * 256 + threadIdx.x;
    if (n < NN) atomicAdd(&ccnt[comm[n]], 1);
}

__global__ void k_cscan(const int* __restrict__ ccnt, int* __restrict__ cstart){
    cstart[0] = 0;
    for (int c = 0; c < NC; c++) cstart[c + 1] = cstart[c] + ccnt[c];
}

__global__ void k_cfill(const int* __restrict__ comm, const int* __restrict__ cstart,
                        int* __restrict__ ccur, int* __restrict__ perm, int* __restrict__ inv){
    int n = blockIdx.x * 256 + threadIdx.x;
    if (n < NN){
        int c = comm[n];
        int p = cstart[c] + atomicAdd(&ccur[c], 1);
        perm[p] = n; inv[n] = p;
    }
}

// ---------------- GEMM: C[4 rows] = A @ W + bias ----------------
template<int M>
__global__ __launch_bounds__(256) void k_gemm(const float* __restrict__ A,
                                              const float* __restrict__ W,
                                              const float* __restrict__ bias,
                                              float* __restrict__ C){
    int n0 = blockIdx.x * 4;
    __shared__ float a[4][DD];
    int tid = threadIdx.x;
    for (int i = tid; i < 4 * DD; i += 256) a[i >> 8][i & 255] = A[(n0 + (i >> 8)) * DD + (i & 255)];
    __syncthreads();
    for (int j = tid; j < M; j += 256){
        float bz = bias[j];
        float a0 = bz, a1 = bz, a2 = bz, a3 = bz;
        #pragma unroll 8
        for (int k = 0; k < DD; k++){
            float wv = W[k * M + j];
            a0 += a[0][k] * wv; a1 += a[1][k] * wv; a2 += a[2][k] * wv; a3 += a[3][k] * wv;
        }
        C[(n0 + 0) * M + j] = a0;
        C[(n0 + 1) * M + j] = a1;
        C[(n0 + 2) * M + j] = a2;
        C[(n0 + 3) * M + j] = a3;
    }
}

// ---------------- residual + layernorm: h = LN(h + t) * g + b ----------------
__global__ __launch_bounds__(256) void k_ln_res(float* __restrict__ h, const float* __restrict__ t,
                                                const float* __restrict__ g, const float* __restrict__ b){
    int n = blockIdx.x, d = threadIdx.x;
    __shared__ float red[256];
    float v = h[n * 256 + d] + t[n * 256 + d];
    red[d] = v; __syncthreads();
    for (int s = 128; s > 0; s >>= 1){ if (d < s) red[d] += red[d + s]; __syncthreads(); }
    float mean = red[0] * (1.0f / 256.0f); __syncthreads();
    float c = v - mean;
    red[d] = c * c; __syncthreads();
    for (int s = 128; s > 0; s >>= 1){ if (d < s) red[d] += red[d + s]; __syncthreads(); }
    float var = red[0] * (1.0f / 256.0f);
    h[n * 256 + d] = c * rsqrtf(var + 1e-5f) * g[d] + b[d];
}

// ---------------- local attention, community-sorted ----------------
// grid (NCMAX/TQ2, NC, HH), 256 threads. Block = TQ2 queries x 1 head x 1 community.
// Dense over the Nc community members; edge bias scattered via inv[].
__global__ __launch_bounds__(256) void k_local_attn2(
        const float* __restrict__ q, const float* __restrict__ k, const float* __restrict__ v,
        const int* __restrict__ cstart, const int* __restrict__ perm, const int* __restrict__ inv,
        const int* __restrict__ rp, const int* __restrict__ e_dst, const int* __restrict__ e_typ,
        const float* __restrict__ eb, float* __restrict__ o){
    int c  = blockIdx.y;
    int hh = blockIdx.z;
    int s  = cstart[c], e = cstart[c + 1];
    int Nc = e - s;
    int p0 = blockIdx.x * TQ2;
    if (p0 >= Nc) return;
    int nq = min(TQ2, Nc - p0);
    int tid = threadIdx.x;

    __shared__ float sc[TQ2][NCMAX];
    __shared__ float qs[TQ2][DHH];
    __shared__ float4 vlds[64][8];
    __shared__ float rbuf[256];
    __shared__ float sm[TQ2];
    __shared__ int qnode[TQ2];

    if (tid < TQ2) qnode[tid] = (tid < nq) ? perm[s + p0 + tid] : -1;
    __syncthreads();
    {
        int qi = tid >> 5, d = tid & 31;   // 8x32 = 256 threads exactly
        qs[qi][d] = (qi < nq) ? q[(size_t)qnode[qi] * DD + hh * DHH + d] : 0.f;
    }
    __syncthreads();

    // QK^T over community members
    const float scale = 0.17677669529663687f; // 1/sqrt(32)
    for (int j = tid; j < Nc; j += 256){
        const float4* kr = (const float4*)(k + (size_t)perm[s + j] * DD + hh * DHH);
        float t[TQ2];
        #pragma unroll
        for (int qi = 0; qi < TQ2; qi++) t[qi] = 0.f;
        #pragma unroll
        for (int d4 = 0; d4 < DHH / 4; d4++){
            float4 kv = kr[d4];
            #pragma unroll
            for (int qi = 0; qi < TQ2; qi++){
                float4 qv = ((const float4*)qs[qi])[d4];
                t[qi] += qv.x * kv.x + qv.y * kv.y + qv.z * kv.z + qv.w * kv.w;
            }
        }
        #pragma unroll
        for (int qi = 0; qi < TQ2; qi++) sc[qi][j] = t[qi] * scale;
    }
    __syncthreads();

    // edge-type bias (duplicates accumulate, matching .at[].add)
    for (int qi = 0; qi < nq; qi++){
        int n = qnode[qi];
        for (int e2 = rp[n] + tid; e2 < rp[n + 1]; e2 += 256){
            int dpos = inv[e_dst[e2]];
            if (dpos >= s && dpos < e)
                atomicAdd(&sc[qi][dpos - s], eb[e_typ[e2] * HH + hh]);
        }
    }
    __syncthreads();

    // softmax, one 32-thread group per row
    {
        int qi = tid >> 5, lane = tid & 31;
        float lm = -1e30f;
        for (int m = lane; m < Nc; m += 32) lm = fmaxf(lm, sc[qi][m]);
        rbuf[tid] = lm; __syncthreads();
        for (int st = 16; st > 0; st >>= 1){
            if (lane < st) rbuf[tid] = fmaxf(rbuf[tid], rbuf[tid + st]);
            __syncthreads();
        }
        float mx = rbuf[qi * 32];
        float ls = 0.f;
        for (int m = lane; m < Nc; m += 32){
            float e_ = __expf(sc[qi][m] - mx);
            sc[qi][m] = e_;
            ls += e_;
        }
        rbuf[tid] = ls; __syncthreads();
        for (int st = 16; st > 0; st >>= 1){
            if (lane < st) rbuf[tid] += rbuf[tid + st];
            __syncthreads();
        }
        if (lane == 0) sm[qi] = rbuf[tid];
    }

    // PV with chunked V staging: thread = (qi, d)
    {
        int qi = tid >> 5, d = tid & 31;
        float acc = 0.f;
        for (int j0 = 0; j0 < Nc; j0 += 64){
            int jn = min(64, Nc - j0);
            __syncthreads();
            for (int f = tid; f < jn * 8; f += 256){
                int r = f >> 3, q4 = f & 7;
                vlds[r][q4] = ((const float4*)(v + (size_t)perm[s + j0 + r] * DD + hh * DHH))[q4];
            }
            __syncthreads();
            for (int j = 0; j < jn; j++)
                acc += sc[qi][j0 + j] * ((const float*)vlds[j])[d];
        }
        if (qi < nq) o[(size_t)qnode[qi] * DD + hh * DHH + d] = acc / sm[qi];
    }
}

// ---------------- global (cross-community) attention ----------------
__global__ __launch_bounds__(256) void k_glob_attn(
        const float* __restrict__ Q, const float* __restrict__ K, const float* __restrict__ V,
        const int* __restrict__ comm, float* __restrict__ o){
    int n0 = blockIdx.x * TQ;
    int tid = threadIdx.x;
    __shared__ float sc[TQ][NN];
    __shared__ float qs[TQ][DD];
    __shared__ float rbuf[256];
    __shared__ int qc[TQ];
    __shared__ float sm[TQ];

    for (int i = tid; i < TQ * DD; i += 256) qs[i >> 8][i & 255] = Q[(n0 + (i >> 8)) * DD + (i & 255)];
    if (tid < TQ) qc[tid] = comm[n0 + tid];
    __syncthreads();

    const float scale = 0.17677669529663687f; // 1/sqrt(32) per reference
    for (int m = tid; m < NN; m += 256){
        int cm = comm[m];
        const float4* kr = (const float4*)(K + (size_t)m * DD);
        float t0 = 0, t1 = 0, t2 = 0, t3 = 0;
        #pragma unroll 8
        for (int d4 = 0; d4 < DD / 4; d4++){
            float4 kv = kr[d4];
            float4 q0 = ((const float4*)qs[0])[d4];
            float4 q1 = ((const float4*)qs[1])[d4];
            float4 q2 = ((const float4*)qs[2])[d4];
            float4 q3 = ((const float4*)qs[3])[d4];
            t0 += q0.x * kv.x + q0.y * kv.y + q0.z * kv.z + q0.w * kv.w;
            t1 += q1.x * kv.x + q1.y * kv.y + q1.z * kv.z + q1.w * kv.w;
            t2 += q2.x * kv.x + q2.y * kv.y + q2.z * kv.z + q2.w * kv.w;
            t3 += q3.x * kv.x + q3.y * kv.y + q3.z * kv.z + q3.w * kv.w;
        }
        sc[0][m] = (cm != qc[0]) ? t0 * scale : -INFINITY;
        sc[1][m] = (cm != qc[1]) ? t1 * scale : -INFINITY;
        sc[2][m] = (cm != qc[2]) ? t2 * scale : -INFINITY;
        sc[3][m] = (cm != qc[3]) ? t3 * scale : -INFINITY;
    }
    __syncthreads();

    for (int qi = 0; qi < TQ; qi++){
        float lm = -INFINITY;
        for (int m = tid; m < NN; m += 256) lm = fmaxf(lm, sc[qi][m]);
        rbuf[tid] = lm; __syncthreads();
        for (int s = 128; s > 0; s >>= 1){ if (tid < s) rbuf[tid] = fmaxf(rbuf[tid], rbuf[tid + s]); __syncthreads(); }
        float mx = rbuf[0]; __syncthreads();
        float ls = 0;
        for (int m = tid; m < NN; m += 256){
            float e_ = __expf(sc[qi][m] - mx);
            sc[qi][m] = e_;
            ls += e_;
        }
        rbuf[tid] = ls; __syncthreads();
        for (int s = 128; s > 0; s >>= 1){ if (tid < s) rbuf[tid] += rbuf[tid + s]; __syncthreads(); }
        if (tid == 0) sm[qi] = rbuf[0];
        __syncthreads();
    }

    float a0 = 0, a1 = 0, a2 = 0, a3 = 0;
    #pragma unroll 4
    for (int m = 0; m < NN; m++){
        float vv = V[(size_t)m * DD + tid];
        a0 += sc[0][m] * vv;
        a1 += sc[1][m] * vv;
        a2 += sc[2][m] * vv;
        a3 += sc[3][m] * vv;
    }
    o[(n0 + 0) * DD + tid] = a0 / sm[0];
    o[(n0 + 1) * DD + tid] = a1 / sm[1];
    o[(n0 + 2) * DD + tid] = a2 / sm[2];
    o[(n0 + 3) * DD + tid] = a3 / sm[3];
}

// ---------------- host ----------------
extern "C" void kernel_launch(void* const* d_in, const int* in_sizes, int n_in,
                              void* d_out, int out_size, void* d_ws, size_t ws_size,
                              hipStream_t stream){
    const float* x        = (const float*)d_in[0];
    const int*   ei       = (const int*)  d_in[1];
    const int*   et       = (const int*)  d_in[2];
    const float* pos      = (const float*)d_in[3];
    const int*   comm     = (const int*)  d_in[4];
    // d_in[5] adj_matrix unused (zeros)
    const float* emb_w    = (const float*)d_in[6];
    const float* emb_b    = (const float*)d_in[7];
    const float* loc_qw   = (const float*)d_in[8];
    const float* loc_qb   = (const float*)d_in[9];
    const float* loc_kw   = (const float*)d_in[10];
    const float* loc_kb   = (const float*)d_in[11];
    const float* loc_vw   = (const float*)d_in[12];
    const float* loc_vb   = (const float*)d_in[13];
    const float* loc_ow   = (const float*)d_in[14];
    const float* loc_ob   = (const float*)d_in[15];
    const float* loc_eb   = (const float*)d_in[16];
    const float* loc_ln_g = (const float*)d_in[17];
    const float* loc_ln_b = (const float*)d_in[18];
    const float* glob_qw  = (const float*)d_in[19];
    const float* glob_qb  = (const float*)d_in[20];
    const float* glob_kw  = (const float*)d_in[21];
    const float* glob_kb  = (const float*)d_in[22];
    const float* glob_vw  = (const float*)d_in[23];
    const float* glob_vb  = (const float*)d_in[24];
    const float* glob_ow  = (const float*)d_in[25];
    const float* glob_ob  = (const float*)d_in[26];
    const float* glob_ln_g= (const float*)d_in[27];
    const float* glob_ln_b= (const float*)d_in[28];
    const float* out_w    = (const float*)d_in[29];
    const float* out_b    = (const float*)d_in[30];

    // workspace carve (fp32 intermediates)
    float* h   = (float*)d_ws;            // NN*DD
    float* hp  = h   + NN * DD;
    float* qb_ = hp  + NN * DD;
    float* kb_ = qb_ + NN * DD;
    float* vb_ = kb_ + NN * DD;
    float* ob_ = vb_ + NN * DD;
    float* tb_ = ob_ + NN * DD;
    int* cnt    = (int*)(tb_ + NN * DD);  // NN
    int* cur    = cnt + NN;               // NN
    int* ccnt   = cur + NN;               // NC
    int* ccur   = ccnt + NC;              // NC
    int* cstart = ccur + NC;              // NC+1
    int* rp     = cstart + NC + 1;        // NN+1
    int* perm   = rp + NN + 1;            // NN
    int* inv    = perm + NN;              // NN
    int* e_dst  = inv + NN;               // EE
    int* e_typ  = e_dst + EE;             // EE

    hipMemsetAsync(cnt, 0, sizeof(int) * (2 * NN + 2 * NC), stream);

    k_embed<<<NN * DD / 256, 256, 0, stream>>>(x, emb_w, emb_b, h);
    k_count<<<EE / 256, 256, 0, stream>>>(ei, cnt);
    k_scan<<<1, 256, 0, stream>>>(cnt, rp);
    k_fill<<<EE / 256, 256, 0, stream>>>(ei, et, rp, cur, e_dst, e_typ);
    k_ccount<<<NN / 256, 256, 0, stream>>>(comm, ccnt);
    k_cscan<<<1, 1, 0, stream>>>(ccnt, cstart);
    k_cfill<<<NN / 256, 256, 0, stream>>>(comm, cstart, ccur, perm, inv);

    for (int l = 0; l < 2; l++){
        k_addpos<<<NN * DD / 256, 256, 0, stream>>>(h, pos, hp);
        k_gemm<DD><<<NN / 4, 256, 0, stream>>>(hp, loc_qw + l * DD * DD, loc_qb + l * DD, qb_);
        k_gemm<DD><<<NN / 4, 256, 0, stream>>>(hp, loc_kw + l * DD * DD, loc_kb + l * DD, kb_);
        k_gemm<DD><<<NN / 4, 256, 0, stream>>>(hp, loc_vw + l * DD * DD, loc_vb + l * DD, vb_);
        k_local_attn2<<<dim3(NCMAX / TQ2, NC, HH), 256, 0, stream>>>(
            qb_, kb_, vb_, cstart, perm, inv, rp, e_dst, e_typ,
            loc_eb + l * NETT * HH, ob_);
        k_gemm<DD><<<NN / 4, 256, 0, stream>>>(ob_, loc_ow + l * DD * DD, loc_ob + l * DD, tb_);
        k_ln_res<<<NN, 256, 0, stream>>>(h, tb_, loc_ln_g + l * DD, loc_ln_b + l * DD);
    }

    for (int g = 0; g < 2; g++){
        k_gemm<DD><<<NN / 4, 256, 0, stream>>>(h, glob_qw + g * DD * DD, glob_qb + g * DD, qb_);
        k_gemm<DD><<<NN / 4, 256, 0, stream>>>(h, glob_kw + g * DD * DD, glob_kb + g * DD, kb_);
        k_gemm<DD><<<NN / 4, 256, 0, stream>>>(h, glob_vw + g * DD * DD, glob_vb + g * DD, vb_);
        k_glob_attn<<<NN / TQ, 256, 0, stream>>>(qb_, kb_, vb_, comm, ob_);
        k_gemm<DD><<<NN / 4, 256, 0, stream>>>(ob_, glob_ow + g * DD * DD, glob_ob + g * DD, tb_);
        k_ln_res<<<NN, 256, 0, stream>>>(h, tb_, glob_ln_g + g * DD, glob_ln_b + g * DD);
    }

    k_gemm<OO><<<NN / 4, 256, 0, stream>>>(h, out_w, out_b, (float*)d_out);
}